// Round 3
// baseline (360.927 us; speedup 1.0000x reference)
//
#include <hip/hip_runtime.h>

// FragAttention: masked prefix-sum along s.
//   x: (S, B, D) f32, src_mask: (B, S) int (True=pad)
//   out: (B, G, 2D) f32, G = S-1
//   left[b,g,d]  = sum_{s<=g} x[s,b,d]*valid[b,s]
//   right[b,g,d] = total[b,d] - left[b,g,d]
//
// R3 = R2 resubmit (R2 bench died to a container-level infra failure; kernel
// audited: loads/stores exactly in-bounds, uniform barriers, legal launch).
//
// Geometry: one block per b, 1024 threads = 128 f4-cols (all of D) x 8
// s-chunks (CS=16). Each chunk (2 waves) writes its 16 g's as FULL 4KB output
// rows in ascending order -> each block emits b's whole 508KB out-slab as one
// dense region (vs R1: 512B fragments at 4KB stride from 2048 scattered
// blocks). Reads: full 2KB (s,b)-planes per chunk.
// v[16] f4 = 64 VGPR (+~25 misc) -> __launch_bounds__(1024,4), no spill.
#define SS 128
#define BB 512
#define DD 512
#define GG 127
#define CS 16    // s-values per thread
#define NC 8     // chunks per block
#define NCOL 128 // float4 columns per block (= all 512 floats of d)

typedef float f4 __attribute__((ext_vector_type(4)));

__global__ __launch_bounds__(1024, 4) void frag_prefix_kernel(
    const float* __restrict__ x, const int* __restrict__ mask,
    float* __restrict__ out) {
  const int tid = threadIdx.x;
  const int b = blockIdx.x;
  const int col = tid & (NCOL - 1);  // float4 column, 0..127
  const int j = tid >> 7;            // s-chunk id, 0..7

  __shared__ float valid[SS];
  __shared__ f4 part[NC][NCOL];

  if (tid < SS) valid[tid] = mask[b * SS + tid] ? 0.0f : 1.0f;
  __syncthreads();

  // x as f4: s-stride = B*D/4 f4's; (s,b)-plane is 2KB = 128 f4.
  const size_t sstride = (size_t)BB * DD / 4;
  const f4* xq = (const f4*)x + (size_t)(j * CS) * sstride +
                 (size_t)b * (DD / 4) + col;

  f4 v[CS];
#pragma unroll
  for (int i = 0; i < CS; ++i) {
    f4 t = __builtin_nontemporal_load(xq + (size_t)i * sstride);
    v[i] = t * valid[j * CS + i];
  }

  f4 psum = v[0];
#pragma unroll
  for (int i = 1; i < CS; ++i) psum += v[i];
  part[j][col] = psum;
  __syncthreads();

  f4 offset = {0.f, 0.f, 0.f, 0.f};
  f4 total = {0.f, 0.f, 0.f, 0.f};
#pragma unroll
  for (int jj = 0; jj < NC; ++jj) {
    f4 p = part[jj][col];
    total += p;
    if (jj < j) offset += p;
  }

  // out[b, g, c]: g-stride = 2*D/4 = 256 f4 (4KB rows); right half at +128.
  f4* op = (f4*)out + (size_t)b * GG * (2 * DD / 4) + col;
  f4 run = offset;
#pragma unroll
  for (int i = 0; i < CS; ++i) {
    run += v[i];
    const int g = j * CS + i;
    if (g < GG) {  // only chunk 7's last iteration skips (wave-uniform)
      __builtin_nontemporal_store(run, op + (size_t)g * (2 * DD / 4));
      f4 r = total - run;
      __builtin_nontemporal_store(r, op + (size_t)g * (2 * DD / 4) + DD / 4);
    }
  }
}

extern "C" void kernel_launch(void* const* d_in, const int* in_sizes, int n_in,
                              void* d_out, int out_size, void* d_ws, size_t ws_size,
                              hipStream_t stream) {
  const float* x = (const float*)d_in[0];
  const int* mask = (const int*)d_in[1];
  float* out = (float*)d_out;
  // One block per b: 512 blocks x 1024 threads.
  frag_prefix_kernel<<<dim3(BB), dim3(1024), 0, stream>>>(x, mask, out);
}